// Round 1
// baseline (589.389 us; speedup 1.0000x reference)
//
#include <hip/hip_runtime.h>
#include <hip/hip_bf16.h>

#define NN 20000   // nodes
#define FD 512     // features
#define NH 8       // heads
#define NE 320000  // edges
#define MP 20096   // padded rows = 157*128

typedef unsigned int u32;
typedef unsigned short u16;
typedef __bf16 bf16x8 __attribute__((ext_vector_type(8)));
typedef float f32x4 __attribute__((ext_vector_type(4)));

#define AS1 __attribute__((address_space(1)))
#define AS3 __attribute__((address_space(3)))

__device__ __forceinline__ u16 f2bf(float f) {
  __hip_bfloat16 h = __float2bfloat16(f);
  union { __hip_bfloat16 b; u16 u; } c; c.b = h; return c.u;
}
__device__ __forceinline__ float bf2f(u32 u) { return __uint_as_float(u << 16); }
__device__ __forceinline__ f32x4 mfma16(bf16x8 a, bf16x8 b, f32x4 c) {
  return __builtin_amdgcn_mfma_f32_16x16x32_bf16(a, b, c, 0, 0, 0);
}
__device__ __forceinline__ void gl_lds16(const void* g, void* l) {
  __builtin_amdgcn_global_load_lds((AS1 void*)const_cast<void*>(g), (AS3 void*)l, 16, 0, 0);
}

// ---- convert feat -> bf16 hi/lo (split), zero pad rows ----
__global__ __launch_bounds__(256) void k_split_feat(const float* __restrict__ feat,
    u16* __restrict__ hi, u16* __restrict__ lo)
{
  size_t i = ((size_t)blockIdx.x * 256 + threadIdx.x) * 4;
  if (i >= (size_t)MP * FD) return;
  float4 v = make_float4(0.f, 0.f, 0.f, 0.f);
  if (i < (size_t)NN * FD) v = *(const float4*)(feat + i);
  float f[4] = {v.x, v.y, v.z, v.w};
  u16 hb[4], lb[4];
#pragma unroll
  for (int j = 0; j < 4; j++) {
    u16 h = f2bf(f[j]);
    hb[j] = h;
    lb[j] = f2bf(f[j] - bf2f(h));
  }
  *(ushort4*)(hi + i) = make_ushort4(hb[0], hb[1], hb[2], hb[3]);
  *(ushort4*)(lo + i) = make_ushort4(lb[0], lb[1], lb[2], lb[3]);
}

// ---- Wq|Wk transposed -> bf16 hi/lo [1024][512] ----
__global__ __launch_bounds__(256) void k_wqk(const float* __restrict__ Wq, const float* __restrict__ Wk,
    u16* __restrict__ Bhi, u16* __restrict__ Blo)
{
  int idx = blockIdx.x * 256 + threadIdx.x; // over 1024*512
  int n = idx >> 9, k = idx & 511;
  float v = (n < FD) ? Wq[k * FD + n] : Wk[k * FD + (n - FD)];
  u16 h = f2bf(v);
  Bhi[idx] = h;
  Blo[idx] = f2bf(v - bf2f(h));
}

// ---- generic W transposed -> bf16 [512][512] ----
__global__ __launch_bounds__(256) void k_wc(const float* __restrict__ W, u16* __restrict__ Bt)
{
  int idx = blockIdx.x * 256 + threadIdx.x; // over 512*512
  int n = idx >> 9, k = idx & 511;
  Bt[idx] = f2bf(W[k * FD + n]);
}

// ---- fold Wgate: gA = w1+w3, gB = w2-w3 ----
__global__ void k_gvec(const float* __restrict__ Wg, float* __restrict__ gA, float* __restrict__ gB)
{
  int j = blockIdx.x * 256 + threadIdx.x;
  if (j >= FD) return;
  gA[j] = Wg[j] + Wg[2 * FD + j];
  gB[j] = Wg[FD + j] - Wg[2 * FD + j];
}

// ---- GEMM: A[M,512] bf16 (row-major, optional lo part) x Bt[N,512] bf16 -> C[M,N]
// MODE: 0=f32 store, 1=relu+bf16, 2=bf16, 3=f32 accumulate into Cf
template<int NCOLS, int MODE, int SPLIT>
__global__ __launch_bounds__(256, 2) void k_gemm(
    const u16* __restrict__ A, const u16* __restrict__ Al,
    const u16* __restrict__ B, const u16* __restrict__ Bl,
    float* __restrict__ Cf, u16* __restrict__ Cb, int Mreal)
{
  constexpr int NSP = SPLIT ? 2 : 1;
  __shared__ u16 sA[NSP][128 * 64];
  __shared__ u16 sB[NSP][128 * 64];
  const int tid = threadIdx.x, lane = tid & 63, w = tid >> 6;
  const int wr = w >> 1, wc = w & 1;
  const long brow = (long)blockIdx.x * 128;
  const long bcol = (long)blockIdx.y * 128;
  const int rl = lane >> 3, cl = (lane & 7) * 8;
  f32x4 acc[4][4] = {};
  for (int kt = 0; kt < FD; kt += 64) {
#pragma unroll
    for (int i = 0; i < 4; i++) {
      int r0 = i * 32 + w * 8;
      long ga = (brow + r0 + rl) * FD + kt + cl;
      long gb = (bcol + r0 + rl) * FD + kt + cl;
      gl_lds16(A + ga, &sA[0][r0 * 64]);
      gl_lds16(B + gb, &sB[0][r0 * 64]);
      if constexpr (SPLIT) {
        gl_lds16(Al + ga, &sA[1][r0 * 64]);
        gl_lds16(Bl + gb, &sB[1][r0 * 64]);
      }
    }
    __syncthreads();
#pragma unroll
    for (int kk = 0; kk < 64; kk += 32) {
      const int ro = kk + (lane >> 4) * 8;
      bf16x8 af[4], bfr[4], afl[4], bfl[4];
#pragma unroll
      for (int m = 0; m < 4; m++) af[m] = *(const bf16x8*)&sA[0][(wr*64 + m*16 + (lane&15))*64 + ro];
#pragma unroll
      for (int n = 0; n < 4; n++) bfr[n] = *(const bf16x8*)&sB[0][(wc*64 + n*16 + (lane&15))*64 + ro];
      if constexpr (SPLIT) {
#pragma unroll
        for (int m = 0; m < 4; m++) afl[m] = *(const bf16x8*)&sA[1][(wr*64 + m*16 + (lane&15))*64 + ro];
#pragma unroll
        for (int n = 0; n < 4; n++) bfl[n] = *(const bf16x8*)&sB[1][(wc*64 + n*16 + (lane&15))*64 + ro];
      }
#pragma unroll
      for (int m = 0; m < 4; m++)
#pragma unroll
        for (int n = 0; n < 4; n++) {
          acc[m][n] = mfma16(af[m], bfr[n], acc[m][n]);
          if constexpr (SPLIT) {
            acc[m][n] = mfma16(af[m], bfl[n], acc[m][n]);
            acc[m][n] = mfma16(afl[m], bfr[n], acc[m][n]);
          }
        }
    }
    __syncthreads();
  }
#pragma unroll
  for (int m = 0; m < 4; m++) {
    long row0 = brow + wr * 64 + m * 16 + (lane >> 4) * 4;
#pragma unroll
    for (int n = 0; n < 4; n++) {
      long col = bcol + wc * 64 + n * 16 + (lane & 15);
#pragma unroll
      for (int j = 0; j < 4; j++) {
        long row = row0 + j;
        if (row < Mreal) {
          float v = acc[m][n][j];
          long o = row * NCOLS + col;
          if constexpr (MODE == 0) Cf[o] = v;
          else if constexpr (MODE == 1) Cb[o] = f2bf(fmaxf(v, 0.f));
          else if constexpr (MODE == 2) Cb[o] = f2bf(v);
          else Cf[o] += v;
        }
      }
    }
  }
}

// ---- CSR build ----
__global__ __launch_bounds__(256) void k_deg(const int* __restrict__ dst, int* __restrict__ deg)
{
  int e = blockIdx.x * 256 + threadIdx.x;
  if (e < NE) atomicAdd(&deg[dst[e]], 1);
}

__global__ void k_scan(const int* __restrict__ deg, int* __restrict__ offa)
{
  __shared__ int buf[1024];
  __shared__ int carry;
  if (threadIdx.x == 0) { carry = 0; offa[0] = 0; }
  __syncthreads();
  for (int base = 0; base < NN; base += 1024) {
    int i = base + threadIdx.x;
    int v = (i < NN) ? deg[i] : 0;
    buf[threadIdx.x] = v;
    __syncthreads();
    for (int s = 1; s < 1024; s <<= 1) {
      int t = (threadIdx.x >= s) ? buf[threadIdx.x - s] : 0;
      __syncthreads();
      buf[threadIdx.x] += t;
      __syncthreads();
    }
    if (i < NN) offa[i + 1] = carry + buf[threadIdx.x];
    __syncthreads();
    if (threadIdx.x == 0) carry += buf[1023];
    __syncthreads();
  }
}

__global__ __launch_bounds__(256) void k_scatter(const int* __restrict__ src, const int* __restrict__ dst,
    const int* __restrict__ offa, int* __restrict__ cnt, int* __restrict__ esrcs, int* __restrict__ eords)
{
  int e = blockIdx.x * 256 + threadIdx.x;
  if (e >= NE) return;
  int d = dst[e];
  int p = offa[d] + atomicAdd(&cnt[d], 1);
  esrcs[p] = src[e];
  eords[p] = e;
}

// ---- per-edge logits: dot(q[src],k[dst]) per head, fixed-max shifted exp, denom atomics ----
__global__ __launch_bounds__(256) void k_logits(const int* __restrict__ src, const int* __restrict__ dst,
    const float* __restrict__ QK, float* __restrict__ exb, float* __restrict__ den)
{
  int e = blockIdx.x * 4 + (threadIdx.x >> 6);
  if (e >= NE) return;
  int lane = threadIdx.x & 63;
  int s = src[e], d = dst[e];
  const float4* qp = (const float4*)(QK + (size_t)s * 1024) + lane * 2;
  const float4* kp = (const float4*)(QK + (size_t)d * 1024 + 512) + lane * 2;
  float4 q0 = qp[0], q1 = qp[1], k0 = kp[0], k1 = kp[1];
  float p = q0.x*k0.x + q0.y*k0.y + q0.z*k0.z + q0.w*k0.w
          + q1.x*k1.x + q1.y*k1.y + q1.z*k1.z + q1.w*k1.w;
  p += __shfl_xor(p, 1);
  p += __shfl_xor(p, 2);
  p += __shfl_xor(p, 4);
  if ((lane & 7) == 0) {
    int h = lane >> 3;
    float l = fminf(fmaxf(p, -5.f), 5.f) * 8.f;     // clip then /SCALING
    float ex = __expf(l - 40.f);                     // fixed max shift, logits in [-40,40]
    exb[(size_t)e * NH + h] = ex;
    atomicAdd(&den[(size_t)d * NH + h], ex);
  }
}

// ---- per-dst-node aggregation (one wave per node, no atomics) -> agg bf16 ----
__global__ __launch_bounds__(256) void k_agg(const int* __restrict__ offa, const int* __restrict__ esrcs,
    const int* __restrict__ eords, const float* __restrict__ exb, const float* __restrict__ den,
    const u16* __restrict__ Vb, u16* __restrict__ aggb)
{
  int nd = blockIdx.x * 4 + (threadIdx.x >> 6);
  int lane = threadIdx.x & 63;
  if (nd >= MP) return;
  uint4* op = (uint4*)(aggb + (size_t)nd * FD + lane * 8);
  if (nd >= NN) { *op = make_uint4(0, 0, 0, 0); return; }
  int h = lane >> 3;
  float rd = 1.f / den[(size_t)nd * NH + h];
  int b0 = offa[nd], b1 = offa[nd + 1];
  float a0=0,a1=0,a2=0,a3=0,a4=0,a5=0,a6=0,a7=0;
  for (int p = b0; p < b1; p++) {
    int s = esrcs[p];
    int eo = eords[p];
    float sa = exb[(size_t)eo * NH + h] * rd;
    uint4 vv = *(const uint4*)(Vb + (size_t)s * FD + lane * 8);
    a0 += sa * bf2f(vv.x & 0xffffu); a1 += sa * bf2f(vv.x >> 16);
    a2 += sa * bf2f(vv.y & 0xffffu); a3 += sa * bf2f(vv.y >> 16);
    a4 += sa * bf2f(vv.z & 0xffffu); a5 += sa * bf2f(vv.z >> 16);
    a6 += sa * bf2f(vv.w & 0xffffu); a7 += sa * bf2f(vv.w >> 16);
  }
  uint4 st;
  st.x = (u32)f2bf(a0) | ((u32)f2bf(a1) << 16);
  st.y = (u32)f2bf(a2) | ((u32)f2bf(a3) << 16);
  st.z = (u32)f2bf(a4) | ((u32)f2bf(a5) << 16);
  st.w = (u32)f2bf(a6) | ((u32)f2bf(a7) << 16);
  *op = st;
}

// ---- gate GEMV + gated residual + LN1 (-> h in d_out) + LN2 (-> bf16) ----
__device__ __forceinline__ float blkred(float v, float* sb)
{
#pragma unroll
  for (int s = 1; s < 64; s <<= 1) v += __shfl_xor(v, s);
  __syncthreads();
  if ((threadIdx.x & 63) == 0) sb[threadIdx.x >> 6] = v;
  __syncthreads();
  return sb[0] + sb[1];
}

__global__ __launch_bounds__(128) void k_gate_ln(const float* __restrict__ rst, const float* __restrict__ skp,
    const float* __restrict__ gA, const float* __restrict__ gB,
    const float* __restrict__ g1, const float* __restrict__ b1,
    const float* __restrict__ g2, const float* __restrict__ b2,
    float* __restrict__ hout, u16* __restrict__ h2b)
{
  __shared__ float sb[2];
  const int t = threadIdx.x;
  const size_t base = (size_t)blockIdx.x * FD + t * 4;
  float4 r = *(const float4*)(rst + base);
  float4 s = *(const float4*)(skp + base);
  float4 a = *(const float4*)(gA + t * 4);
  float4 b = *(const float4*)(gB + t * 4);
  float gd = r.x*a.x + r.y*a.y + r.z*a.z + r.w*a.w
           + s.x*b.x + s.y*b.y + s.z*b.z + s.w*b.w;
  float tot = blkred(gd, sb);
  float g = 1.f / (1.f + __expf(-tot));
  float x0 = g*r.x + (1.f-g)*s.x;
  float x1 = g*r.y + (1.f-g)*s.y;
  float x2 = g*r.z + (1.f-g)*s.z;
  float x3 = g*r.w + (1.f-g)*s.w;
  float m1 = blkred(x0+x1+x2+x3, sb) * (1.f/FD);
  float d0 = x0-m1, d1 = x1-m1, d2 = x2-m1, d3 = x3-m1;
  float v1 = blkred(d0*d0+d1*d1+d2*d2+d3*d3, sb) * (1.f/FD);
  float rs = rsqrtf(v1 + 1e-5f);
  float4 G1 = *(const float4*)(g1 + t*4);
  float4 Bb1 = *(const float4*)(b1 + t*4);
  float h0 = d0*rs*G1.x + Bb1.x;
  float h1 = d1*rs*G1.y + Bb1.y;
  float h2 = d2*rs*G1.z + Bb1.z;
  float h3 = d3*rs*G1.w + Bb1.w;
  *(float4*)(hout + base) = make_float4(h0, h1, h2, h3);
  float m2 = blkred(h0+h1+h2+h3, sb) * (1.f/FD);
  float e0 = h0-m2, e1 = h1-m2, e2 = h2-m2, e3 = h3-m2;
  float v2 = blkred(e0*e0+e1*e1+e2*e2+e3*e3, sb) * (1.f/FD);
  float rs2 = rsqrtf(v2 + 1e-5f);
  float4 G2 = *(const float4*)(g2 + t*4);
  float4 Bb2 = *(const float4*)(b2 + t*4);
  *(ushort4*)(h2b + base) = make_ushort4(
      f2bf(e0*rs2*G2.x + Bb2.x), f2bf(e1*rs2*G2.y + Bb2.y),
      f2bf(e2*rs2*G2.z + Bb2.z), f2bf(e3*rs2*G2.w + Bb2.w));
}

extern "C" void kernel_launch(void* const* d_in, const int* in_sizes, int n_in,
                              void* d_out, int out_size, void* d_ws, size_t ws_size,
                              hipStream_t stream)
{
  const float* feat = (const float*)d_in[0];
  const int* e_src = (const int*)d_in[1];
  const int* e_dst = (const int*)d_in[2];
  const float* Wq  = (const float*)d_in[3];
  const float* Wk  = (const float*)d_in[4];
  const float* Wv  = (const float*)d_in[5];
  const float* Wn  = (const float*)d_in[6];
  const float* Wsk = (const float*)d_in[7];
  const float* Wg  = (const float*)d_in[8];
  const float* l1g = (const float*)d_in[9];
  const float* l1b = (const float*)d_in[10];
  const float* l2g = (const float*)d_in[11];
  const float* l2b = (const float*)d_in[12];
  const float* W1  = (const float*)d_in[13];
  const float* W2  = (const float*)d_in[14];

  char* ws = (char*)d_ws;
  size_t o = 0;
  auto al = [&](size_t b) { char* r = ws + o; o = (o + b + 255) & ~(size_t)255; return r; };

  u16* Ahi  = (u16*)al((size_t)MP * FD * 2);
  u16* Alo  = (u16*)al((size_t)MP * FD * 2);
  u16* Bqkh = (u16*)al((size_t)1024 * FD * 2);
  u16* Bqkl = (u16*)al((size_t)1024 * FD * 2);
  u16* Bvt  = (u16*)al((size_t)FD * FD * 2);
  u16* Bst  = (u16*)al((size_t)FD * FD * 2);
  u16* Bnt  = (u16*)al((size_t)FD * FD * 2);
  u16* B1t  = (u16*)al((size_t)FD * FD * 2);
  u16* B2t  = (u16*)al((size_t)FD * FD * 2);
  float* gA = (float*)al(FD * 4);
  float* gB = (float*)al(FD * 4);
  float* QK = (float*)al((size_t)MP * 1024 * 4);   // [Q|K] fp32
  u16* Vb   = (u16*)al((size_t)MP * FD * 2);
  float* SKIP = (float*)al((size_t)MP * FD * 4);
  int* deg  = (int*)al((size_t)2 * NN * 4);
  int* cnt  = deg + NN;
  int* offa = (int*)al((size_t)(NN + 1) * 4);
  int* esrcs = (int*)al((size_t)NE * 4);
  int* eords = (int*)al((size_t)NE * 4);
  float* exb = (float*)al((size_t)NE * NH * 4);
  float* den = (float*)al((size_t)NN * NH * 4);
  if (o > ws_size) return;  // ~204 MB needed
  // aliases into dead regions
  u16* aggb  = (u16*)QK;                                   // QK dead after k_logits
  float* rst = (float*)((char*)QK + (size_t)MP * FD * 2);  // disjoint from aggb
  u16* h2b   = Alo;                                        // Alo dead after QK GEMM
  u16* midb  = Ahi;                                        // Ahi dead after V/SKIP GEMMs
  float* out = (float*)d_out;

  hipMemsetAsync(deg, 0, (size_t)2 * NN * 4, stream);
  hipMemsetAsync(den, 0, (size_t)NN * NH * 4, stream);

  k_split_feat<<<dim3(MP * FD / 4 / 256), 256, 0, stream>>>(feat, Ahi, Alo);
  k_wqk<<<dim3(1024 * FD / 256), 256, 0, stream>>>(Wq, Wk, Bqkh, Bqkl);
  k_wc<<<dim3(FD * FD / 256), 256, 0, stream>>>(Wv, Bvt);
  k_wc<<<dim3(FD * FD / 256), 256, 0, stream>>>(Wsk, Bst);
  k_wc<<<dim3(FD * FD / 256), 256, 0, stream>>>(Wn, Bnt);
  k_wc<<<dim3(FD * FD / 256), 256, 0, stream>>>(W1, B1t);
  k_wc<<<dim3(FD * FD / 256), 256, 0, stream>>>(W2, B2t);
  k_gvec<<<dim3(2), 256, 0, stream>>>(Wg, gA, gB);

  // Q|K via split-bf16 (fp32-class precision); V and SKIP plain bf16
  k_gemm<1024, 0, 1><<<dim3(MP / 128, 8), 256, 0, stream>>>(Ahi, Alo, Bqkh, Bqkl, QK, nullptr, MP);
  k_gemm<512, 2, 0><<<dim3(MP / 128, 4), 256, 0, stream>>>(Ahi, nullptr, Bvt, nullptr, nullptr, Vb, MP);
  k_gemm<512, 0, 0><<<dim3(MP / 128, 4), 256, 0, stream>>>(Ahi, nullptr, Bst, nullptr, SKIP, nullptr, MP);

  k_deg<<<dim3((NE + 255) / 256), 256, 0, stream>>>(e_dst, deg);
  k_scan<<<dim3(1), 1024, 0, stream>>>(deg, offa);
  k_scatter<<<dim3((NE + 255) / 256), 256, 0, stream>>>(e_src, e_dst, offa, cnt, esrcs, eords);
  k_logits<<<dim3((NE + 3) / 4), 256, 0, stream>>>(e_src, e_dst, QK, exb, den);
  k_agg<<<dim3((MP + 3) / 4), 256, 0, stream>>>(offa, esrcs, eords, exb, den, Vb, aggb);

  k_gemm<512, 0, 0><<<dim3(MP / 128, 4), 256, 0, stream>>>(aggb, nullptr, Bnt, nullptr, rst, nullptr, MP);
  k_gate_ln<<<dim3(NN), 128, 0, stream>>>(rst, SKIP, gA, gB, l1g, l1b, l2g, l2b, out, h2b);
  k_gemm<512, 1, 0><<<dim3(MP / 128, 4), 256, 0, stream>>>(h2b, nullptr, B1t, nullptr, nullptr, midb, MP);
  k_gemm<512, 3, 0><<<dim3(MP / 128, 4), 256, 0, stream>>>(midb, nullptr, B2t, nullptr, out, nullptr, NN);
}

// Round 2
// 430.342 us; speedup vs baseline: 1.3696x; 1.3696x over previous
//
#include <hip/hip_runtime.h>
#include <hip/hip_bf16.h>
#include <hip/hip_fp16.h>

#define NN 20000   // nodes
#define FD 512     // features
#define NH 8       // heads
#define NE 320000  // edges
#define MP 20096   // padded rows = 157*128

typedef unsigned int u32;
typedef unsigned short u16;
typedef __bf16 bf16x8 __attribute__((ext_vector_type(8)));
typedef float f32x4 __attribute__((ext_vector_type(4)));

#define AS1 __attribute__((address_space(1)))
#define AS3 __attribute__((address_space(3)))

__device__ __forceinline__ u16 f2bf(float f) {
  __hip_bfloat16 h = __float2bfloat16(f);
  union { __hip_bfloat16 b; u16 u; } c; c.b = h; return c.u;
}
__device__ __forceinline__ float bf2f(u32 u) { return __uint_as_float(u << 16); }
__device__ __forceinline__ u16 f2h(float f) {
  union { __half h; u16 u; } c; c.h = __float2half(f); return c.u;
}
__device__ __forceinline__ f32x4 mfma16(bf16x8 a, bf16x8 b, f32x4 c) {
  return __builtin_amdgcn_mfma_f32_16x16x32_bf16(a, b, c, 0, 0, 0);
}
__device__ __forceinline__ void gl_lds16(const void* g, void* l) {
  __builtin_amdgcn_global_load_lds((AS1 void*)const_cast<void*>(g), (AS3 void*)l, 16, 0, 0);
}
__device__ __forceinline__ void up_h8(uint4 w, float* f) {
  union { u32 u; __half2 h; } c;
  c.u = w.x; float2 t0 = __half22float2(c.h); f[0]=t0.x; f[1]=t0.y;
  c.u = w.y; float2 t1 = __half22float2(c.h); f[2]=t1.x; f[3]=t1.y;
  c.u = w.z; float2 t2 = __half22float2(c.h); f[4]=t2.x; f[5]=t2.y;
  c.u = w.w; float2 t3 = __half22float2(c.h); f[6]=t3.x; f[7]=t3.y;
}
__device__ __forceinline__ void up_b8(uint4 w, float* f) {
  f[0]=bf2f(w.x & 0xffffu); f[1]=bf2f(w.x >> 16);
  f[2]=bf2f(w.y & 0xffffu); f[3]=bf2f(w.y >> 16);
  f[4]=bf2f(w.z & 0xffffu); f[5]=bf2f(w.z >> 16);
  f[6]=bf2f(w.w & 0xffffu); f[7]=bf2f(w.w >> 16);
}

// ---- convert feat -> bf16 hi/lo (split), zero pad rows ----
__global__ __launch_bounds__(256) void k_split_feat(const float* __restrict__ feat,
    u16* __restrict__ hi, u16* __restrict__ lo)
{
  size_t i = ((size_t)blockIdx.x * 256 + threadIdx.x) * 4;
  if (i >= (size_t)MP * FD) return;
  float4 v = make_float4(0.f, 0.f, 0.f, 0.f);
  if (i < (size_t)NN * FD) v = *(const float4*)(feat + i);
  float f[4] = {v.x, v.y, v.z, v.w};
  u16 hb[4], lb[4];
#pragma unroll
  for (int j = 0; j < 4; j++) {
    u16 h = f2bf(f[j]);
    hb[j] = h;
    lb[j] = f2bf(f[j] - bf2f(h));
  }
  *(ushort4*)(hi + i) = make_ushort4(hb[0], hb[1], hb[2], hb[3]);
  *(ushort4*)(lo + i) = make_ushort4(lb[0], lb[1], lb[2], lb[3]);
}

// ---- Wq|Wk transposed -> bf16 hi/lo [1024][512] ----
__global__ __launch_bounds__(256) void k_wqk(const float* __restrict__ Wq, const float* __restrict__ Wk,
    u16* __restrict__ Bhi, u16* __restrict__ Blo)
{
  int idx = blockIdx.x * 256 + threadIdx.x; // over 1024*512
  int n = idx >> 9, k = idx & 511;
  float v = (n < FD) ? Wq[k * FD + n] : Wk[k * FD + (n - FD)];
  u16 h = f2bf(v);
  Bhi[idx] = h;
  Blo[idx] = f2bf(v - bf2f(h));
}

// ---- generic W transposed -> bf16 [512][512] ----
__global__ __launch_bounds__(256) void k_wc(const float* __restrict__ W, u16* __restrict__ Bt)
{
  int idx = blockIdx.x * 256 + threadIdx.x; // over 512*512
  int n = idx >> 9, k = idx & 511;
  Bt[idx] = f2bf(W[k * FD + n]);
}

// ---- fold Wgate: gA = w1+w3, gB = w2-w3 ----
__global__ void k_gvec(const float* __restrict__ Wg, float* __restrict__ gA, float* __restrict__ gB)
{
  int j = blockIdx.x * 256 + threadIdx.x;
  if (j >= FD) return;
  gA[j] = Wg[j] + Wg[2 * FD + j];
  gB[j] = Wg[FD + j] - Wg[2 * FD + j];
}

// ---- GEMM: A[M,512] bf16 (row-major, optional lo part) x Bt[N,512] bf16 -> C[M,N]
// MODE: 0=f32 store, 1=relu+bf16, 2=bf16, 3=f32 accumulate into Cf, 4=fp16 store
template<int NCOLS, int MODE, int SPLIT>
__global__ __launch_bounds__(256, 2) void k_gemm(
    const u16* __restrict__ A, const u16* __restrict__ Al,
    const u16* __restrict__ B, const u16* __restrict__ Bl,
    float* __restrict__ Cf, u16* __restrict__ Cb, int Mreal)
{
  constexpr int NSP = SPLIT ? 2 : 1;
  __shared__ u16 sA[NSP][128 * 64];
  __shared__ u16 sB[NSP][128 * 64];
  const int tid = threadIdx.x, lane = tid & 63, w = tid >> 6;
  const int wr = w >> 1, wc = w & 1;
  const long brow = (long)blockIdx.x * 128;
  const long bcol = (long)blockIdx.y * 128;
  const int rl = lane >> 3, cl = (lane & 7) * 8;
  f32x4 acc[4][4] = {};
  for (int kt = 0; kt < FD; kt += 64) {
#pragma unroll
    for (int i = 0; i < 4; i++) {
      int r0 = i * 32 + w * 8;
      long ga = (brow + r0 + rl) * FD + kt + cl;
      long gb = (bcol + r0 + rl) * FD + kt + cl;
      gl_lds16(A + ga, &sA[0][r0 * 64]);
      gl_lds16(B + gb, &sB[0][r0 * 64]);
      if constexpr (SPLIT) {
        gl_lds16(Al + ga, &sA[1][r0 * 64]);
        gl_lds16(Bl + gb, &sB[1][r0 * 64]);
      }
    }
    __syncthreads();
#pragma unroll
    for (int kk = 0; kk < 64; kk += 32) {
      const int ro = kk + (lane >> 4) * 8;
      bf16x8 af[4], bfr[4], afl[4], bfl[4];
#pragma unroll
      for (int m = 0; m < 4; m++) af[m] = *(const bf16x8*)&sA[0][(wr*64 + m*16 + (lane&15))*64 + ro];
#pragma unroll
      for (int n = 0; n < 4; n++) bfr[n] = *(const bf16x8*)&sB[0][(wc*64 + n*16 + (lane&15))*64 + ro];
      if constexpr (SPLIT) {
#pragma unroll
        for (int m = 0; m < 4; m++) afl[m] = *(const bf16x8*)&sA[1][(wr*64 + m*16 + (lane&15))*64 + ro];
#pragma unroll
        for (int n = 0; n < 4; n++) bfl[n] = *(const bf16x8*)&sB[1][(wc*64 + n*16 + (lane&15))*64 + ro];
      }
#pragma unroll
      for (int m = 0; m < 4; m++)
#pragma unroll
        for (int n = 0; n < 4; n++) {
          acc[m][n] = mfma16(af[m], bfr[n], acc[m][n]);
          if constexpr (SPLIT) {
            acc[m][n] = mfma16(af[m], bfl[n], acc[m][n]);
            acc[m][n] = mfma16(afl[m], bfr[n], acc[m][n]);
          }
        }
    }
    __syncthreads();
  }
#pragma unroll
  for (int m = 0; m < 4; m++) {
    long row0 = brow + wr * 64 + m * 16 + (lane >> 4) * 4;
#pragma unroll
    for (int n = 0; n < 4; n++) {
      long col = bcol + wc * 64 + n * 16 + (lane & 15);
#pragma unroll
      for (int j = 0; j < 4; j++) {
        long row = row0 + j;
        if (row < Mreal) {
          float v = acc[m][n][j];
          long o = row * NCOLS + col;
          if constexpr (MODE == 0) Cf[o] = v;
          else if constexpr (MODE == 1) Cb[o] = f2bf(fmaxf(v, 0.f));
          else if constexpr (MODE == 2) Cb[o] = f2bf(v);
          else if constexpr (MODE == 3) Cf[o] += v;
          else Cb[o] = f2h(v);
        }
      }
    }
  }
}

// ---- CSR build ----
__global__ __launch_bounds__(256) void k_deg(const int* __restrict__ dst, int* __restrict__ deg)
{
  int e = blockIdx.x * 256 + threadIdx.x;
  if (e < NE) atomicAdd(&deg[dst[e]], 1);
}

__global__ void k_scan(const int* __restrict__ deg, int* __restrict__ offa)
{
  __shared__ int buf[1024];
  __shared__ int carry;
  if (threadIdx.x == 0) { carry = 0; offa[0] = 0; }
  __syncthreads();
  for (int base = 0; base < NN; base += 1024) {
    int i = base + threadIdx.x;
    int v = (i < NN) ? deg[i] : 0;
    buf[threadIdx.x] = v;
    __syncthreads();
    for (int s = 1; s < 1024; s <<= 1) {
      int t = (threadIdx.x >= s) ? buf[threadIdx.x - s] : 0;
      __syncthreads();
      buf[threadIdx.x] += t;
      __syncthreads();
    }
    if (i < NN) offa[i + 1] = carry + buf[threadIdx.x];
    __syncthreads();
    if (threadIdx.x == 0) carry += buf[1023];
    __syncthreads();
  }
}

__global__ __launch_bounds__(256) void k_scatter(const int* __restrict__ src, const int* __restrict__ dst,
    const int* __restrict__ offa, int* __restrict__ cnt, int* __restrict__ esrcs)
{
  int e = blockIdx.x * 256 + threadIdx.x;
  if (e >= NE) return;
  int d = dst[e];
  int p = offa[d] + atomicAdd(&cnt[d], 1);
  esrcs[p] = src[e];
}

// ---- fused per-dst-node edge pass: logits + fixed-shift softmax + V aggregation ----
// one wave per dst node; lane l covers head l>>3, dims (l&7)*8..+8  (== halfs [8l,8l+8))
__global__ __launch_bounds__(256) void k_edge(const int* __restrict__ offa,
    const int* __restrict__ esrcs, const u16* __restrict__ QK,
    const u16* __restrict__ Vb, u16* __restrict__ aggb)
{
  int nd = blockIdx.x * 4 + (threadIdx.x >> 6);
  int lane = threadIdx.x & 63;
  if (nd >= MP) return;
  uint4* op = (uint4*)(aggb + (size_t)nd * FD + lane * 8);
  if (nd >= NN) { *op = make_uint4(0, 0, 0, 0); return; }
  uint4 kw = *(const uint4*)(QK + (size_t)nd * 1024 + 512 + lane * 8);
  float kx[8]; up_h8(kw, kx);
  int b0 = offa[nd], b1 = offa[nd + 1];
  float den = 0.f;
  float a[8] = {0,0,0,0,0,0,0,0};
  int p = b0;
  for (; p + 2 <= b1; p += 2) {
    int s0 = esrcs[p], s1 = esrcs[p + 1];
    uint4 qw0 = *(const uint4*)(QK + (size_t)s0 * 1024 + lane * 8);
    uint4 vv0 = *(const uint4*)(Vb + (size_t)s0 * FD + lane * 8);
    uint4 qw1 = *(const uint4*)(QK + (size_t)s1 * 1024 + lane * 8);
    uint4 vv1 = *(const uint4*)(Vb + (size_t)s1 * FD + lane * 8);
    float qx[8], vx[8];
    up_h8(qw0, qx);
    float d0 = qx[0]*kx[0]+qx[1]*kx[1]+qx[2]*kx[2]+qx[3]*kx[3]
             + qx[4]*kx[4]+qx[5]*kx[5]+qx[6]*kx[6]+qx[7]*kx[7];
    d0 += __shfl_xor(d0, 1); d0 += __shfl_xor(d0, 2); d0 += __shfl_xor(d0, 4);
    float ex0 = __expf(fminf(fmaxf(d0, -5.f), 5.f) * 8.f - 40.f);
    den += ex0;
    up_b8(vv0, vx);
#pragma unroll
    for (int j = 0; j < 8; j++) a[j] += ex0 * vx[j];
    up_h8(qw1, qx);
    float d1 = qx[0]*kx[0]+qx[1]*kx[1]+qx[2]*kx[2]+qx[3]*kx[3]
             + qx[4]*kx[4]+qx[5]*kx[5]+qx[6]*kx[6]+qx[7]*kx[7];
    d1 += __shfl_xor(d1, 1); d1 += __shfl_xor(d1, 2); d1 += __shfl_xor(d1, 4);
    float ex1 = __expf(fminf(fmaxf(d1, -5.f), 5.f) * 8.f - 40.f);
    den += ex1;
    up_b8(vv1, vx);
#pragma unroll
    for (int j = 0; j < 8; j++) a[j] += ex1 * vx[j];
  }
  if (p < b1) {
    int s0 = esrcs[p];
    uint4 qw0 = *(const uint4*)(QK + (size_t)s0 * 1024 + lane * 8);
    uint4 vv0 = *(const uint4*)(Vb + (size_t)s0 * FD + lane * 8);
    float qx[8], vx[8];
    up_h8(qw0, qx);
    float d0 = qx[0]*kx[0]+qx[1]*kx[1]+qx[2]*kx[2]+qx[3]*kx[3]
             + qx[4]*kx[4]+qx[5]*kx[5]+qx[6]*kx[6]+qx[7]*kx[7];
    d0 += __shfl_xor(d0, 1); d0 += __shfl_xor(d0, 2); d0 += __shfl_xor(d0, 4);
    float ex0 = __expf(fminf(fmaxf(d0, -5.f), 5.f) * 8.f - 40.f);
    den += ex0;
    up_b8(vv0, vx);
#pragma unroll
    for (int j = 0; j < 8; j++) a[j] += ex0 * vx[j];
  }
  float rd = 1.f / den;
  uint4 st;
  st.x = (u32)f2bf(a[0]*rd) | ((u32)f2bf(a[1]*rd) << 16);
  st.y = (u32)f2bf(a[2]*rd) | ((u32)f2bf(a[3]*rd) << 16);
  st.z = (u32)f2bf(a[4]*rd) | ((u32)f2bf(a[5]*rd) << 16);
  st.w = (u32)f2bf(a[6]*rd) | ((u32)f2bf(a[7]*rd) << 16);
  *op = st;
}

// ---- gate GEMV + gated residual + LN1 (-> h in d_out) + LN2 (-> bf16) ----
__device__ __forceinline__ float blkred(float v, float* sb)
{
#pragma unroll
  for (int s = 1; s < 64; s <<= 1) v += __shfl_xor(v, s);
  __syncthreads();
  if ((threadIdx.x & 63) == 0) sb[threadIdx.x >> 6] = v;
  __syncthreads();
  return sb[0] + sb[1];
}

__global__ __launch_bounds__(128) void k_gate_ln(const float* __restrict__ rst, const float* __restrict__ skp,
    const float* __restrict__ gA, const float* __restrict__ gB,
    const float* __restrict__ g1, const float* __restrict__ b1,
    const float* __restrict__ g2, const float* __restrict__ b2,
    float* __restrict__ hout, u16* __restrict__ h2b)
{
  __shared__ float sb[2];
  const int t = threadIdx.x;
  const size_t base = (size_t)blockIdx.x * FD + t * 4;
  float4 r = *(const float4*)(rst + base);
  float4 s = *(const float4*)(skp + base);
  float4 a = *(const float4*)(gA + t * 4);
  float4 b = *(const float4*)(gB + t * 4);
  float gd = r.x*a.x + r.y*a.y + r.z*a.z + r.w*a.w
           + s.x*b.x + s.y*b.y + s.z*b.z + s.w*b.w;
  float tot = blkred(gd, sb);
  float g = 1.f / (1.f + __expf(-tot));
  float x0 = g*r.x + (1.f-g)*s.x;
  float x1 = g*r.y + (1.f-g)*s.y;
  float x2 = g*r.z + (1.f-g)*s.z;
  float x3 = g*r.w + (1.f-g)*s.w;
  float m1 = blkred(x0+x1+x2+x3, sb) * (1.f/FD);
  float d0 = x0-m1, d1 = x1-m1, d2 = x2-m1, d3 = x3-m1;
  float v1 = blkred(d0*d0+d1*d1+d2*d2+d3*d3, sb) * (1.f/FD);
  float rs = rsqrtf(v1 + 1e-5f);
  float4 G1 = *(const float4*)(g1 + t*4);
  float4 Bb1 = *(const float4*)(b1 + t*4);
  float h0 = d0*rs*G1.x + Bb1.x;
  float h1 = d1*rs*G1.y + Bb1.y;
  float h2 = d2*rs*G1.z + Bb1.z;
  float h3 = d3*rs*G1.w + Bb1.w;
  *(float4*)(hout + base) = make_float4(h0, h1, h2, h3);
  float m2 = blkred(h0+h1+h2+h3, sb) * (1.f/FD);
  float e0 = h0-m2, e1 = h1-m2, e2 = h2-m2, e3 = h3-m2;
  float v2 = blkred(e0*e0+e1*e1+e2*e2+e3*e3, sb) * (1.f/FD);
  float rs2 = rsqrtf(v2 + 1e-5f);
  float4 G2 = *(const float4*)(g2 + t*4);
  float4 Bb2 = *(const float4*)(b2 + t*4);
  *(ushort4*)(h2b + base) = make_ushort4(
      f2bf(e0*rs2*G2.x + Bb2.x), f2bf(e1*rs2*G2.y + Bb2.y),
      f2bf(e2*rs2*G2.z + Bb2.z), f2bf(e3*rs2*G2.w + Bb2.w));
}

extern "C" void kernel_launch(void* const* d_in, const int* in_sizes, int n_in,
                              void* d_out, int out_size, void* d_ws, size_t ws_size,
                              hipStream_t stream)
{
  const float* feat = (const float*)d_in[0];
  const int* e_src = (const int*)d_in[1];
  const int* e_dst = (const int*)d_in[2];
  const float* Wq  = (const float*)d_in[3];
  const float* Wk  = (const float*)d_in[4];
  const float* Wv  = (const float*)d_in[5];
  const float* Wn  = (const float*)d_in[6];
  const float* Wsk = (const float*)d_in[7];
  const float* Wg  = (const float*)d_in[8];
  const float* l1g = (const float*)d_in[9];
  const float* l1b = (const float*)d_in[10];
  const float* l2g = (const float*)d_in[11];
  const float* l2b = (const float*)d_in[12];
  const float* W1  = (const float*)d_in[13];
  const float* W2  = (const float*)d_in[14];

  char* ws = (char*)d_ws;
  size_t o = 0;
  auto al = [&](size_t b) { char* r = ws + o; o = (o + b + 255) & ~(size_t)255; return r; };

  u16* Ahi  = (u16*)al((size_t)MP * FD * 2);
  u16* Alo  = (u16*)al((size_t)MP * FD * 2);
  u16* Bqkh = (u16*)al((size_t)1024 * FD * 2);
  u16* Bqkl = (u16*)al((size_t)1024 * FD * 2);
  u16* Bvt  = (u16*)al((size_t)FD * FD * 2);
  u16* Bst  = (u16*)al((size_t)FD * FD * 2);
  u16* Bnt  = (u16*)al((size_t)FD * FD * 2);
  u16* B1t  = (u16*)al((size_t)FD * FD * 2);
  u16* B2t  = (u16*)al((size_t)FD * FD * 2);
  float* gA = (float*)al(FD * 4);
  float* gB = (float*)al(FD * 4);
  u16* QKh  = (u16*)al((size_t)MP * 1024 * 2);  // [Q|K] fp16
  u16* aggb = (u16*)al((size_t)MP * FD * 2);
  u16* Vb   = (u16*)al((size_t)MP * FD * 2);
  float* SKIP = (float*)al((size_t)MP * FD * 4);
  int* deg  = (int*)al((size_t)2 * NN * 4);
  int* cnt  = deg + NN;
  int* offa = (int*)al((size_t)(NN + 1) * 4);
  int* esrcs = (int*)al((size_t)NE * 4);
  if (o > ws_size) return;  // ~170 MB needed
  // aliases into dead regions
  float* rst = (float*)QKh;   // QKh (41.2MB) dead after k_edge; rst needs MP*512*4 = 41.2MB
  u16* h2b   = Alo;           // Alo dead after QK GEMM
  u16* midb  = Ahi;           // Ahi dead after V/SKIP GEMMs
  float* out = (float*)d_out;

  hipMemsetAsync(deg, 0, (size_t)2 * NN * 4, stream);

  k_split_feat<<<dim3(MP * FD / 4 / 256), 256, 0, stream>>>(feat, Ahi, Alo);
  k_wqk<<<dim3(1024 * FD / 256), 256, 0, stream>>>(Wq, Wk, Bqkh, Bqkl);
  k_wc<<<dim3(FD * FD / 256), 256, 0, stream>>>(Wv, Bvt);
  k_wc<<<dim3(FD * FD / 256), 256, 0, stream>>>(Wsk, Bst);
  k_wc<<<dim3(FD * FD / 256), 256, 0, stream>>>(Wn, Bnt);
  k_wc<<<dim3(FD * FD / 256), 256, 0, stream>>>(W1, B1t);
  k_wc<<<dim3(FD * FD / 256), 256, 0, stream>>>(W2, B2t);
  k_gvec<<<dim3(2), 256, 0, stream>>>(Wg, gA, gB);

  // Q|K via split-bf16 (fp32-class accum, fp16 store); V and SKIP plain bf16
  k_gemm<1024, 4, 1><<<dim3(MP / 128, 8), 256, 0, stream>>>(Ahi, Alo, Bqkh, Bqkl, nullptr, QKh, MP);
  k_gemm<512, 2, 0><<<dim3(MP / 128, 4), 256, 0, stream>>>(Ahi, nullptr, Bvt, nullptr, nullptr, Vb, MP);
  k_gemm<512, 0, 0><<<dim3(MP / 128, 4), 256, 0, stream>>>(Ahi, nullptr, Bst, nullptr, SKIP, nullptr, MP);

  k_deg<<<dim3((NE + 255) / 256), 256, 0, stream>>>(e_dst, deg);
  k_scan<<<dim3(1), 1024, 0, stream>>>(deg, offa);
  k_scatter<<<dim3((NE + 255) / 256), 256, 0, stream>>>(e_src, e_dst, offa, cnt, esrcs);
  k_edge<<<dim3((MP + 3) / 4), 256, 0, stream>>>(offa, esrcs, QKh, Vb, aggb);

  k_gemm<512, 0, 0><<<dim3(MP / 128, 4), 256, 0, stream>>>(aggb, nullptr, Bnt, nullptr, rst, nullptr, MP);
  k_gate_ln<<<dim3(NN), 128, 0, stream>>>(rst, SKIP, gA, gB, l1g, l1b, l2g, l2b, out, h2b);
  k_gemm<512, 1, 0><<<dim3(MP / 128, 4), 256, 0, stream>>>(h2b, nullptr, B1t, nullptr, nullptr, midb, MP);
  k_gemm<512, 3, 0><<<dim3(MP / 128, 4), 256, 0, stream>>>(midb, nullptr, B2t, nullptr, out, nullptr, NN);
}

// Round 3
// 412.559 us; speedup vs baseline: 1.4286x; 1.0431x over previous
//
#include <hip/hip_runtime.h>
#include <hip/hip_bf16.h>
#include <hip/hip_fp16.h>

#define NN 20000   // nodes
#define FD 512     // features
#define NH 8       // heads
#define NE 320000  // edges
#define MP 20096   // padded rows = 157*128

typedef unsigned int u32;
typedef unsigned short u16;
typedef __bf16 bf16x8 __attribute__((ext_vector_type(8)));
typedef float f32x4 __attribute__((ext_vector_type(4)));

#define AS1 __attribute__((address_space(1)))
#define AS3 __attribute__((address_space(3)))

__device__ __forceinline__ u16 f2bf(float f) {
  __hip_bfloat16 h = __float2bfloat16(f);
  union { __hip_bfloat16 b; u16 u; } c; c.b = h; return c.u;
}
__device__ __forceinline__ float bf2f(u32 u) { return __uint_as_float(u << 16); }
__device__ __forceinline__ u16 f2h(float f) {
  union { __half h; u16 u; } c; c.h = __float2half(f); return c.u;
}
__device__ __forceinline__ f32x4 mfma16(bf16x8 a, bf16x8 b, f32x4 c) {
  return __builtin_amdgcn_mfma_f32_16x16x32_bf16(a, b, c, 0, 0, 0);
}
__device__ __forceinline__ void gl_lds16(const void* g, void* l) {
  __builtin_amdgcn_global_load_lds((AS1 void*)const_cast<void*>(g), (AS3 void*)l, 16, 0, 0);
}
__device__ __forceinline__ void up_h8(uint4 w, float* f) {
  union { u32 u; __half2 h; } c;
  c.u = w.x; float2 t0 = __half22float2(c.h); f[0]=t0.x; f[1]=t0.y;
  c.u = w.y; float2 t1 = __half22float2(c.h); f[2]=t1.x; f[3]=t1.y;
  c.u = w.z; float2 t2 = __half22float2(c.h); f[4]=t2.x; f[5]=t2.y;
  c.u = w.w; float2 t3 = __half22float2(c.h); f[6]=t3.x; f[7]=t3.y;
}
__device__ __forceinline__ void up_b8(uint4 w, float* f) {
  f[0]=bf2f(w.x & 0xffffu); f[1]=bf2f(w.x >> 16);
  f[2]=bf2f(w.y & 0xffffu); f[3]=bf2f(w.y >> 16);
  f[4]=bf2f(w.z & 0xffffu); f[5]=bf2f(w.z >> 16);
  f[6]=bf2f(w.w & 0xffffu); f[7]=bf2f(w.w >> 16);
}

// ---- convert feat -> bf16 hi/lo (split), zero pad rows ----
__global__ __launch_bounds__(256) void k_split_feat(const float* __restrict__ feat,
    u16* __restrict__ hi, u16* __restrict__ lo)
{
  size_t i = ((size_t)blockIdx.x * 256 + threadIdx.x) * 4;
  if (i >= (size_t)MP * FD) return;
  float4 v = make_float4(0.f, 0.f, 0.f, 0.f);
  if (i < (size_t)NN * FD) v = *(const float4*)(feat + i);
  float f[4] = {v.x, v.y, v.z, v.w};
  u16 hb[4], lb[4];
#pragma unroll
  for (int j = 0; j < 4; j++) {
    u16 h = f2bf(f[j]);
    hb[j] = h;
    lb[j] = f2bf(f[j] - bf2f(h));
  }
  *(ushort4*)(hi + i) = make_ushort4(hb[0], hb[1], hb[2], hb[3]);
  *(ushort4*)(lo + i) = make_ushort4(lb[0], lb[1], lb[2], lb[3]);
}

// ---- all weight prep in one kernel ----
__global__ __launch_bounds__(256) void k_wprep(
    const float* __restrict__ Wq, const float* __restrict__ Wk,
    const float* __restrict__ Wv, const float* __restrict__ Wsk,
    const float* __restrict__ Wn, const float* __restrict__ W1,
    const float* __restrict__ W2, const float* __restrict__ Wg,
    u16* __restrict__ Bqkh, u16* __restrict__ Bqkl, u16* __restrict__ Bvs,
    u16* __restrict__ Bnt, u16* __restrict__ B1t, u16* __restrict__ B2t,
    float* __restrict__ gA, float* __restrict__ gB)
{
  int idx = blockIdx.x * 256 + threadIdx.x;
  if (idx < 1024 * 512) {              // QK hi/lo transposed
    int n = idx >> 9, k = idx & 511;
    float v = (n < 512) ? Wq[k * 512 + n] : Wk[k * 512 + (n - 512)];
    u16 h = f2bf(v);
    Bqkh[idx] = h; Bqkl[idx] = f2bf(v - bf2f(h));
    return;
  }
  idx -= 1024 * 512;
  if (idx < 1024 * 512) {              // [Wv|Wsk] transposed
    int n = idx >> 9, k = idx & 511;
    float v = (n < 512) ? Wv[k * 512 + n] : Wsk[k * 512 + (n - 512)];
    Bvs[idx] = f2bf(v);
    return;
  }
  idx -= 1024 * 512;
  if (idx < 512 * 512) { int n = idx >> 9, k = idx & 511; Bnt[idx] = f2bf(Wn[k * 512 + n]); return; }
  idx -= 512 * 512;
  if (idx < 512 * 512) { int n = idx >> 9, k = idx & 511; B1t[idx] = f2bf(W1[k * 512 + n]); return; }
  idx -= 512 * 512;
  if (idx < 512 * 512) { int n = idx >> 9, k = idx & 511; B2t[idx] = f2bf(W2[k * 512 + n]); return; }
  idx -= 512 * 512;
  if (idx < 512) {
    gA[idx] = Wg[idx] + Wg[2 * 512 + idx];
    gB[idx] = Wg[512 + idx] - Wg[2 * 512 + idx];
  }
}

// ---- GEMM: A[M,512] bf16 x Bt[NCOLS,512] bf16 -> epilogue by MODE
// MODE: 0=f32, 1=relu+bf16, 2=bf16, 3=f32 accumulate,
//       4=QK fp16 split-store (col<512 -> Cb=QV q-half stride1024; else Cb2=Kb stride512)
//       5=V|SKIP bf16 store (col<512 -> Cb=QV v-half at +512, stride1024; else Cb2=SKIPb stride512)
template<int NCOLS, int MODE, int SPLIT>
__global__ __launch_bounds__(256, 2) void k_gemm(
    const u16* __restrict__ A, const u16* __restrict__ Al,
    const u16* __restrict__ B, const u16* __restrict__ Bl,
    float* __restrict__ Cf, u16* __restrict__ Cb, u16* __restrict__ Cb2, int Mreal)
{
  constexpr int NSP = SPLIT ? 2 : 1;
  __shared__ u16 sA[NSP][128 * 64];
  __shared__ u16 sB[NSP][128 * 64];
  const int tid = threadIdx.x, lane = tid & 63, w = tid >> 6;
  const int wr = w >> 1, wc = w & 1;
  const long brow = (long)blockIdx.x * 128;
  const long bcol = (long)blockIdx.y * 128;
  const int rl = lane >> 3, cl = (lane & 7) * 8;
  f32x4 acc[4][4] = {};
  for (int kt = 0; kt < FD; kt += 64) {
#pragma unroll
    for (int i = 0; i < 4; i++) {
      int r0 = i * 32 + w * 8;
      long ga = (brow + r0 + rl) * FD + kt + cl;
      long gb = (bcol + r0 + rl) * FD + kt + cl;
      gl_lds16(A + ga, &sA[0][r0 * 64]);
      gl_lds16(B + gb, &sB[0][r0 * 64]);
      if constexpr (SPLIT) {
        gl_lds16(Al + ga, &sA[1][r0 * 64]);
        gl_lds16(Bl + gb, &sB[1][r0 * 64]);
      }
    }
    __syncthreads();
#pragma unroll
    for (int kk = 0; kk < 64; kk += 32) {
      const int ro = kk + (lane >> 4) * 8;
      bf16x8 af[4], bfr[4], afl[4], bfl[4];
#pragma unroll
      for (int m = 0; m < 4; m++) af[m] = *(const bf16x8*)&sA[0][(wr*64 + m*16 + (lane&15))*64 + ro];
#pragma unroll
      for (int n = 0; n < 4; n++) bfr[n] = *(const bf16x8*)&sB[0][(wc*64 + n*16 + (lane&15))*64 + ro];
      if constexpr (SPLIT) {
#pragma unroll
        for (int m = 0; m < 4; m++) afl[m] = *(const bf16x8*)&sA[1][(wr*64 + m*16 + (lane&15))*64 + ro];
#pragma unroll
        for (int n = 0; n < 4; n++) bfl[n] = *(const bf16x8*)&sB[1][(wc*64 + n*16 + (lane&15))*64 + ro];
      }
#pragma unroll
      for (int m = 0; m < 4; m++)
#pragma unroll
        for (int n = 0; n < 4; n++) {
          acc[m][n] = mfma16(af[m], bfr[n], acc[m][n]);
          if constexpr (SPLIT) {
            acc[m][n] = mfma16(af[m], bfl[n], acc[m][n]);
            acc[m][n] = mfma16(afl[m], bfr[n], acc[m][n]);
          }
        }
    }
    __syncthreads();
  }
#pragma unroll
  for (int m = 0; m < 4; m++) {
    long row0 = brow + wr * 64 + m * 16 + (lane >> 4) * 4;
#pragma unroll
    for (int n = 0; n < 4; n++) {
      long col = bcol + wc * 64 + n * 16 + (lane & 15);
#pragma unroll
      for (int j = 0; j < 4; j++) {
        long row = row0 + j;
        if (row < Mreal) {
          float v = acc[m][n][j];
          if constexpr (MODE == 0) Cf[row * NCOLS + col] = v;
          else if constexpr (MODE == 1) Cb[row * NCOLS + col] = f2bf(fmaxf(v, 0.f));
          else if constexpr (MODE == 2) Cb[row * NCOLS + col] = f2bf(v);
          else if constexpr (MODE == 3) Cf[row * NCOLS + col] += v;
          else if constexpr (MODE == 4) {
            if (col < 512) Cb[row * 1024 + col] = f2h(v);
            else           Cb2[row * 512 + (col - 512)] = f2h(v);
          } else {
            if (col < 512) Cb[row * 1024 + 512 + col] = f2bf(v);
            else           Cb2[row * 512 + (col - 512)] = f2bf(v);
          }
        }
      }
    }
  }
}

// ---- CSR build ----
__global__ __launch_bounds__(256) void k_deg(const int* __restrict__ dst, int* __restrict__ deg)
{
  int e = blockIdx.x * 256 + threadIdx.x;
  if (e < NE) atomicAdd(&deg[dst[e]], 1);
}

__global__ void k_scan(const int* __restrict__ deg, int* __restrict__ offa)
{
  __shared__ int buf[1024];
  __shared__ int carry;
  if (threadIdx.x == 0) { carry = 0; offa[0] = 0; }
  __syncthreads();
  for (int base = 0; base < NN; base += 1024) {
    int i = base + threadIdx.x;
    int v = (i < NN) ? deg[i] : 0;
    buf[threadIdx.x] = v;
    __syncthreads();
    for (int s = 1; s < 1024; s <<= 1) {
      int t = (threadIdx.x >= s) ? buf[threadIdx.x - s] : 0;
      __syncthreads();
      buf[threadIdx.x] += t;
      __syncthreads();
    }
    if (i < NN) offa[i + 1] = carry + buf[threadIdx.x];
    __syncthreads();
    if (threadIdx.x == 0) carry += buf[1023];
    __syncthreads();
  }
}

__global__ __launch_bounds__(256) void k_scatter(const int* __restrict__ src, const int* __restrict__ dst,
    const int* __restrict__ offa, int* __restrict__ cnt, int* __restrict__ esrcs)
{
  int e = blockIdx.x * 256 + threadIdx.x;
  if (e >= NE) return;
  int d = dst[e];
  int p = offa[d] + atomicAdd(&cnt[d], 1);
  esrcs[p] = src[e];
}

// ---- fused per-dst-node edge pass: logits + fixed-shift softmax + V aggregation ----
// one wave per dst node; lane l covers head l>>3, feature dims [8l,8l+8)
// QV row: [q fp16 512 | v bf16 512]; Kb row: k fp16 512
__device__ __forceinline__ float dot8(const float* a, const float* b) {
  return a[0]*b[0]+a[1]*b[1]+a[2]*b[2]+a[3]*b[3]
       + a[4]*b[4]+a[5]*b[5]+a[6]*b[6]+a[7]*b[7];
}

__global__ __launch_bounds__(256) void k_edge(const int* __restrict__ offa,
    const int* __restrict__ esrcs, const u16* __restrict__ QV,
    const u16* __restrict__ Kb, u16* __restrict__ aggb)
{
  int nd = blockIdx.x * 4 + (threadIdx.x >> 6);
  int lane = threadIdx.x & 63;
  if (nd >= MP) return;
  uint4* op = (uint4*)(aggb + (size_t)nd * FD + lane * 8);
  if (nd >= NN) { *op = make_uint4(0, 0, 0, 0); return; }
  uint4 kw = *(const uint4*)(Kb + (size_t)nd * 512 + lane * 8);
  float kx[8]; up_h8(kw, kx);
  int b0 = offa[nd], b1 = offa[nd + 1];
  float den = 0.f;
  float a[8] = {0,0,0,0,0,0,0,0};
  int p = b0;
  for (; p + 4 <= b1; p += 4) {
    int ss[4];
#pragma unroll
    for (int u = 0; u < 4; u++) ss[u] = esrcs[p + u];
    uint4 qw[4], vw[4];
#pragma unroll
    for (int u = 0; u < 4; u++) {
      const u16* r = QV + (size_t)ss[u] * 1024 + lane * 8;
      qw[u] = *(const uint4*)r;
      vw[u] = *(const uint4*)(r + 512);
    }
#pragma unroll
    for (int u = 0; u < 4; u++) {
      float qx[8], vx[8];
      up_h8(qw[u], qx);
      float d = dot8(qx, kx);
      d += __shfl_xor(d, 1); d += __shfl_xor(d, 2); d += __shfl_xor(d, 4);
      float ex = __expf(fminf(fmaxf(d, -5.f), 5.f) * 8.f - 40.f);
      den += ex;
      up_b8(vw[u], vx);
#pragma unroll
      for (int j = 0; j < 8; j++) a[j] += ex * vx[j];
    }
  }
  for (; p < b1; p++) {
    int s = esrcs[p];
    const u16* r = QV + (size_t)s * 1024 + lane * 8;
    uint4 qw0 = *(const uint4*)r;
    uint4 vw0 = *(const uint4*)(r + 512);
    float qx[8], vx[8];
    up_h8(qw0, qx);
    float d = dot8(qx, kx);
    d += __shfl_xor(d, 1); d += __shfl_xor(d, 2); d += __shfl_xor(d, 4);
    float ex = __expf(fminf(fmaxf(d, -5.f), 5.f) * 8.f - 40.f);
    den += ex;
    up_b8(vw0, vx);
#pragma unroll
    for (int j = 0; j < 8; j++) a[j] += ex * vx[j];
  }
  float rd = 1.f / den;
  uint4 st;
  st.x = (u32)f2bf(a[0]*rd) | ((u32)f2bf(a[1]*rd) << 16);
  st.y = (u32)f2bf(a[2]*rd) | ((u32)f2bf(a[3]*rd) << 16);
  st.z = (u32)f2bf(a[4]*rd) | ((u32)f2bf(a[5]*rd) << 16);
  st.w = (u32)f2bf(a[6]*rd) | ((u32)f2bf(a[7]*rd) << 16);
  *op = st;
}

// ---- gate GEMV + gated residual + LN1 (-> h in d_out) + LN2 (-> bf16) ----
__device__ __forceinline__ float blkred(float v, float* sb)
{
#pragma unroll
  for (int s = 1; s < 64; s <<= 1) v += __shfl_xor(v, s);
  __syncthreads();
  if ((threadIdx.x & 63) == 0) sb[threadIdx.x >> 6] = v;
  __syncthreads();
  return sb[0] + sb[1];
}

__global__ __launch_bounds__(128) void k_gate_ln(const u16* __restrict__ rstb, const u16* __restrict__ skpb,
    const float* __restrict__ gA, const float* __restrict__ gB,
    const float* __restrict__ g1, const float* __restrict__ b1,
    const float* __restrict__ g2, const float* __restrict__ b2,
    float* __restrict__ hout, u16* __restrict__ h2b)
{
  __shared__ float sb[2];
  const int t = threadIdx.x;
  const size_t base = (size_t)blockIdx.x * FD + t * 4;
  ushort4 ru = *(const ushort4*)(rstb + base);
  ushort4 su = *(const ushort4*)(skpb + base);
  float r0 = bf2f(ru.x), r1 = bf2f(ru.y), r2 = bf2f(ru.z), r3 = bf2f(ru.w);
  float s0 = bf2f(su.x), s1 = bf2f(su.y), s2 = bf2f(su.z), s3 = bf2f(su.w);
  float4 av = *(const float4*)(gA + t * 4);
  float4 bv = *(const float4*)(gB + t * 4);
  float gd = r0*av.x + r1*av.y + r2*av.z + r3*av.w
           + s0*bv.x + s1*bv.y + s2*bv.z + s3*bv.w;
  float tot = blkred(gd, sb);
  float g = 1.f / (1.f + __expf(-tot));
  float x0 = g*r0 + (1.f-g)*s0;
  float x1 = g*r1 + (1.f-g)*s1;
  float x2 = g*r2 + (1.f-g)*s2;
  float x3 = g*r3 + (1.f-g)*s3;
  float m1 = blkred(x0+x1+x2+x3, sb) * (1.f/FD);
  float d0 = x0-m1, d1 = x1-m1, d2 = x2-m1, d3 = x3-m1;
  float v1 = blkred(d0*d0+d1*d1+d2*d2+d3*d3, sb) * (1.f/FD);
  float rs = rsqrtf(v1 + 1e-5f);
  float4 G1 = *(const float4*)(g1 + t*4);
  float4 Bb1 = *(const float4*)(b1 + t*4);
  float h0 = d0*rs*G1.x + Bb1.x;
  float h1 = d1*rs*G1.y + Bb1.y;
  float h2 = d2*rs*G1.z + Bb1.z;
  float h3 = d3*rs*G1.w + Bb1.w;
  *(float4*)(hout + base) = make_float4(h0, h1, h2, h3);
  float m2 = blkred(h0+h1+h2+h3, sb) * (1.f/FD);
  float e0 = h0-m2, e1 = h1-m2, e2 = h2-m2, e3 = h3-m2;
  float v2 = blkred(e0*e0+e1*e1+e2*e2+e3*e3, sb) * (1.f/FD);
  float rs2 = rsqrtf(v2 + 1e-5f);
  float4 G2 = *(const float4*)(g2 + t*4);
  float4 Bb2 = *(const float4*)(b2 + t*4);
  *(ushort4*)(h2b + base) = make_ushort4(
      f2bf(e0*rs2*G2.x + Bb2.x), f2bf(e1*rs2*G2.y + Bb2.y),
      f2bf(e2*rs2*G2.z + Bb2.z), f2bf(e3*rs2*G2.w + Bb2.w));
}

extern "C" void kernel_launch(void* const* d_in, const int* in_sizes, int n_in,
                              void* d_out, int out_size, void* d_ws, size_t ws_size,
                              hipStream_t stream)
{
  const float* feat = (const float*)d_in[0];
  const int* e_src = (const int*)d_in[1];
  const int* e_dst = (const int*)d_in[2];
  const float* Wq  = (const float*)d_in[3];
  const float* Wk  = (const float*)d_in[4];
  const float* Wv  = (const float*)d_in[5];
  const float* Wn  = (const float*)d_in[6];
  const float* Wsk = (const float*)d_in[7];
  const float* Wg  = (const float*)d_in[8];
  const float* l1g = (const float*)d_in[9];
  const float* l1b = (const float*)d_in[10];
  const float* l2g = (const float*)d_in[11];
  const float* l2b = (const float*)d_in[12];
  const float* W1  = (const float*)d_in[13];
  const float* W2  = (const float*)d_in[14];

  char* ws = (char*)d_ws;
  size_t o = 0;
  auto al = [&](size_t b) { char* r = ws + o; o = (o + b + 255) & ~(size_t)255; return r; };

  u16* Ahi  = (u16*)al((size_t)MP * FD * 2);
  u16* Alo  = (u16*)al((size_t)MP * FD * 2);
  u16* Bqkh = (u16*)al((size_t)1024 * FD * 2);
  u16* Bqkl = (u16*)al((size_t)1024 * FD * 2);
  u16* Bvs  = (u16*)al((size_t)1024 * FD * 2);
  u16* Bnt  = (u16*)al((size_t)FD * FD * 2);
  u16* B1t  = (u16*)al((size_t)FD * FD * 2);
  u16* B2t  = (u16*)al((size_t)FD * FD * 2);
  float* gA = (float*)al(FD * 4);
  float* gB = (float*)al(FD * 4);
  u16* QV   = (u16*)al((size_t)MP * 1024 * 2);  // [q fp16 | v bf16] per node
  u16* Kb   = (u16*)al((size_t)MP * FD * 2);    // k fp16
  u16* SKIPb= (u16*)al((size_t)MP * FD * 2);
  u16* aggb = (u16*)al((size_t)MP * FD * 2);
  int* deg  = (int*)al((size_t)2 * NN * 4);
  int* cnt  = deg + NN;
  int* offa = (int*)al((size_t)(NN + 1) * 4);
  int* esrcs = (int*)al((size_t)NE * 4);
  if (o > ws_size) return;  // ~150 MB needed
  // aliases into dead regions
  u16* rstb = Kb;    // Kb dead after k_edge
  u16* h2b  = Alo;   // Alo dead after QK GEMM
  u16* midb = Ahi;   // Ahi dead after QK+VS GEMMs
  float* out = (float*)d_out;

  hipMemsetAsync(deg, 0, (size_t)2 * NN * 4, stream);

  k_split_feat<<<dim3(MP * FD / 4 / 256), 256, 0, stream>>>(feat, Ahi, Alo);
  {
    int total = 1024*512*2 + 3*512*512 + 512;
    k_wprep<<<dim3((total + 255) / 256), 256, 0, stream>>>(Wq, Wk, Wv, Wsk, Wn, W1, W2, Wg,
        Bqkh, Bqkl, Bvs, Bnt, B1t, B2t, gA, gB);
  }

  // Q|K via split-bf16 (fp32-class accum, fp16 store into QV q-half + Kb)
  k_gemm<1024, 4, 1><<<dim3(MP / 128, 8), 256, 0, stream>>>(Ahi, Alo, Bqkh, Bqkl, nullptr, QV, Kb, MP);
  // V|SKIP merged (bf16 store into QV v-half + SKIPb)
  k_gemm<1024, 5, 0><<<dim3(MP / 128, 8), 256, 0, stream>>>(Ahi, nullptr, Bvs, nullptr, nullptr, QV, SKIPb, MP);

  k_deg<<<dim3((NE + 255) / 256), 256, 0, stream>>>(e_dst, deg);
  k_scan<<<dim3(1), 1024, 0, stream>>>(deg, offa);
  k_scatter<<<dim3((NE + 255) / 256), 256, 0, stream>>>(e_src, e_dst, offa, cnt, esrcs);
  k_edge<<<dim3((MP + 3) / 4), 256, 0, stream>>>(offa, esrcs, QV, Kb, aggb);

  k_gemm<512, 2, 0><<<dim3(MP / 128, 4), 256, 0, stream>>>(aggb, nullptr, Bnt, nullptr, nullptr, rstb, nullptr, MP);
  k_gate_ln<<<dim3(NN), 128, 0, stream>>>(rstb, SKIPb, gA, gB, l1g, l1b, l2g, l2b, out, h2b);
  k_gemm<512, 1, 0><<<dim3(MP / 128, 4), 256, 0, stream>>>(h2b, nullptr, B1t, nullptr, nullptr, midb, nullptr, MP);
  k_gemm<512, 3, 0><<<dim3(MP / 128, 4), 256, 0, stream>>>(midb, nullptr, B2t, nullptr, out, nullptr, nullptr, NN);
}

// Round 4
// 369.851 us; speedup vs baseline: 1.5936x; 1.1155x over previous
//
#include <hip/hip_runtime.h>
#include <hip/hip_bf16.h>
#include <hip/hip_fp16.h>

#define NN 20000   // nodes
#define FD 512     // features
#define NH 8       // heads
#define NE 320000  // edges
#define MP 20096   // padded rows = 157*128

typedef unsigned int u32;
typedef unsigned short u16;
typedef __bf16 bf16x8 __attribute__((ext_vector_type(8)));
typedef _Float16 f16x8 __attribute__((ext_vector_type(8)));
typedef float f32x4 __attribute__((ext_vector_type(4)));

#define AS1 __attribute__((address_space(1)))
#define AS3 __attribute__((address_space(3)))

__device__ __forceinline__ u16 f2bf(float f) {
  __hip_bfloat16 h = __float2bfloat16(f);
  union { __hip_bfloat16 b; u16 u; } c; c.b = h; return c.u;
}
__device__ __forceinline__ float bf2f(u32 u) { return __uint_as_float(u << 16); }
__device__ __forceinline__ u16 f2h(float f) {
  union { __half h; u16 u; } c; c.h = __float2half(f); return c.u;
}
__device__ __forceinline__ void gl_lds16(const void* g, void* l) {
  __builtin_amdgcn_global_load_lds((AS1 void*)const_cast<void*>(g), (AS3 void*)l, 16, 0, 0);
}
__device__ __forceinline__ void up_h4(uint2 w, float* f) {
  union { u32 u; __half2 h; } c;
  c.u = w.x; float2 t0 = __half22float2(c.h); f[0]=t0.x; f[1]=t0.y;
  c.u = w.y; float2 t1 = __half22float2(c.h); f[2]=t1.x; f[3]=t1.y;
}

// ---- feat -> fp16, zero pad rows ----
__global__ __launch_bounds__(256) void k_cvt_feat(const float* __restrict__ feat, u16* __restrict__ Af)
{
  size_t i = ((size_t)blockIdx.x * 256 + threadIdx.x) * 4;
  if (i >= (size_t)MP * FD) return;
  float4 v = make_float4(0.f, 0.f, 0.f, 0.f);
  if (i < (size_t)NN * FD) v = *(const float4*)(feat + i);
  *(ushort4*)(Af + i) = make_ushort4(f2h(v.x), f2h(v.y), f2h(v.z), f2h(v.w));
}

// ---- all weight prep in one kernel ----
// Bqkvs fp16 [2048][512] = [Wq|Wk|Wv|Wsk]^T ; Bnt/B1t/B2t bf16 [512][512]^T ; gA/gB folded gate
__global__ __launch_bounds__(256) void k_wprep(
    const float* __restrict__ Wq, const float* __restrict__ Wk,
    const float* __restrict__ Wv, const float* __restrict__ Wsk,
    const float* __restrict__ Wn, const float* __restrict__ W1,
    const float* __restrict__ W2, const float* __restrict__ Wg,
    u16* __restrict__ Bqkvs, u16* __restrict__ Bnt, u16* __restrict__ B1t,
    u16* __restrict__ B2t, float* __restrict__ gA, float* __restrict__ gB)
{
  int idx = blockIdx.x * 256 + threadIdx.x;
  if (idx < 2048 * 512) {
    int n = idx >> 9, k = idx & 511;
    float v;
    if (n < 512)       v = Wq[k * 512 + n];
    else if (n < 1024) v = Wk[k * 512 + (n - 512)];
    else if (n < 1536) v = Wv[k * 512 + (n - 1024)];
    else               v = Wsk[k * 512 + (n - 1536)];
    Bqkvs[idx] = f2h(v);
    return;
  }
  idx -= 2048 * 512;
  if (idx < 512 * 512) { int n = idx >> 9, k = idx & 511; Bnt[idx] = f2bf(Wn[k * 512 + n]); return; }
  idx -= 512 * 512;
  if (idx < 512 * 512) { int n = idx >> 9, k = idx & 511; B1t[idx] = f2bf(W1[k * 512 + n]); return; }
  idx -= 512 * 512;
  if (idx < 512 * 512) { int n = idx >> 9, k = idx & 511; B2t[idx] = f2bf(W2[k * 512 + n]); return; }
  idx -= 512 * 512;
  if (idx < 512) {
    gA[idx] = Wg[idx] + Wg[2 * 512 + idx];
    gB[idx] = Wg[512 + idx] - Wg[2 * 512 + idx];
  }
}

// ---- GEMM: A[M,512] x Bt[NCOLS,512] (both u16-encoded, FP16 or bf16) ----
// MODE: 1=relu+bf16->Cb, 2=bf16->Cb, 3=f32 accumulate->Cf,
//       6=QKVS split store: col<512 q->Cb(QV,stride1024 fp16); <1024 k->Cb2(fp16);
//                           <1536 v->Cb(QV+512 fp16); else skip->Cb3(bf16)
template<int NCOLS, int MODE, int FP16>
__global__ __launch_bounds__(256, 2) void k_gemm(
    const u16* __restrict__ A, const u16* __restrict__ B,
    float* __restrict__ Cf, u16* __restrict__ Cb, u16* __restrict__ Cb2,
    u16* __restrict__ Cb3, int Mreal)
{
  __shared__ u16 sA[128 * 64];
  __shared__ u16 sB[128 * 64];
  const int tid = threadIdx.x, lane = tid & 63, w = tid >> 6;
  const int wr = w >> 1, wc = w & 1;
  const long brow = (long)blockIdx.x * 128;
  const long bcol = (long)blockIdx.y * 128;
  const int rl = lane >> 3, cl = (lane & 7) * 8;
  f32x4 acc[4][4] = {};
  for (int kt = 0; kt < FD; kt += 64) {
#pragma unroll
    for (int i = 0; i < 4; i++) {
      int r0 = i * 32 + w * 8;
      gl_lds16(A + (brow + r0 + rl) * FD + kt + cl, &sA[r0 * 64]);
      gl_lds16(B + (bcol + r0 + rl) * FD + kt + cl, &sB[r0 * 64]);
    }
    __syncthreads();
#pragma unroll
    for (int kk = 0; kk < 64; kk += 32) {
      const int ro = kk + (lane >> 4) * 8;
#pragma unroll
      for (int m = 0; m < 4; m++) {
        const u16* pa = &sA[(wr*64 + m*16 + (lane&15))*64 + ro];
#pragma unroll
        for (int n = 0; n < 4; n++) {
          const u16* pb = &sB[(wc*64 + n*16 + (lane&15))*64 + ro];
          if constexpr (FP16)
            acc[m][n] = __builtin_amdgcn_mfma_f32_16x16x32_f16(
                *(const f16x8*)pa, *(const f16x8*)pb, acc[m][n], 0, 0, 0);
          else
            acc[m][n] = __builtin_amdgcn_mfma_f32_16x16x32_bf16(
                *(const bf16x8*)pa, *(const bf16x8*)pb, acc[m][n], 0, 0, 0);
        }
      }
    }
    __syncthreads();
  }
#pragma unroll
  for (int m = 0; m < 4; m++) {
    long row0 = brow + wr * 64 + m * 16 + (lane >> 4) * 4;
#pragma unroll
    for (int n = 0; n < 4; n++) {
      long col = bcol + wc * 64 + n * 16 + (lane & 15);
#pragma unroll
      for (int j = 0; j < 4; j++) {
        long row = row0 + j;
        if (row < Mreal) {
          float v = acc[m][n][j];
          if constexpr (MODE == 1) Cb[row * NCOLS + col] = f2bf(fmaxf(v, 0.f));
          else if constexpr (MODE == 2) Cb[row * NCOLS + col] = f2bf(v);
          else if constexpr (MODE == 3) Cf[row * NCOLS + col] += v;
          else {
            if (col < 512)       Cb[row * 1024 + col] = f2h(v);
            else if (col < 1024) Cb2[row * 512 + (col - 512)] = f2h(v);
            else if (col < 1536) Cb[row * 1024 + 512 + (col - 1024)] = f2h(v);
            else                 Cb3[row * 512 + (col - 1536)] = f2bf(v);
          }
        }
      }
    }
  }
}

// ---- CSR build ----
__global__ __launch_bounds__(256) void k_deg(const int* __restrict__ dst, int* __restrict__ deg)
{
  int e = blockIdx.x * 256 + threadIdx.x;
  if (e < NE) atomicAdd(&deg[dst[e]], 1);
}

__global__ void k_scan(const int* __restrict__ deg, int* __restrict__ offa)
{
  __shared__ int buf[1024];
  __shared__ int carry;
  if (threadIdx.x == 0) { carry = 0; offa[0] = 0; }
  __syncthreads();
  for (int base = 0; base < NN; base += 1024) {
    int i = base + threadIdx.x;
    int v = (i < NN) ? deg[i] : 0;
    buf[threadIdx.x] = v;
    __syncthreads();
    for (int s = 1; s < 1024; s <<= 1) {
      int t = (threadIdx.x >= s) ? buf[threadIdx.x - s] : 0;
      __syncthreads();
      buf[threadIdx.x] += t;
      __syncthreads();
    }
    if (i < NN) offa[i + 1] = carry + buf[threadIdx.x];
    __syncthreads();
    if (threadIdx.x == 0) carry += buf[1023];
    __syncthreads();
  }
}

__global__ __launch_bounds__(256) void k_scatter(const int* __restrict__ src, const int* __restrict__ dst,
    const int* __restrict__ offa, int* __restrict__ cnt, int* __restrict__ esrcs)
{
  int e = blockIdx.x * 256 + threadIdx.x;
  if (e >= NE) return;
  int d = dst[e];
  int p = offa[d] + atomicAdd(&cnt[d], 1);
  esrcs[p] = src[e];
}

// ---- fused edge pass: 2 waves per dst node (4 heads each), 8-edge batches ----
// QV row: [q fp16 512 | v fp16 512]; Kb row: k fp16 512
// wave covers dims [half*256, half*256+256); lane covers 4 dims; 16 lanes = 1 head
__global__ __launch_bounds__(256) void k_edge(const int* __restrict__ offa,
    const int* __restrict__ esrcs, const u16* __restrict__ QV,
    const u16* __restrict__ Kb, u16* __restrict__ aggb)
{
  int wid = blockIdx.x * 4 + (threadIdx.x >> 6);
  int nd = wid >> 1, half = wid & 1;
  int lane = threadIdx.x & 63;
  if (nd >= MP) return;
  const int off = half * 256 + lane * 4;
  u16* op = aggb + (size_t)nd * FD + off;
  if (nd >= NN) { *(ushort4*)op = make_ushort4(0, 0, 0, 0); return; }
  uint2 kw = *(const uint2*)(Kb + (size_t)nd * 512 + off);
  float kx[4]; up_h4(kw, kx);
  int b0 = offa[nd], b1 = offa[nd + 1];
  float den = 0.f, a0 = 0.f, a1 = 0.f, a2 = 0.f, a3 = 0.f;
  for (int p = b0; p < b1; p += 8) {
    int ss[8]; uint2 qw[8], vw[8];
#pragma unroll
    for (int u = 0; u < 8; u++) { int ix = p + u; ss[u] = esrcs[ix < b1 ? ix : b1 - 1]; }
#pragma unroll
    for (int u = 0; u < 8; u++) {
      const u16* r = QV + (size_t)ss[u] * 1024 + off;
      qw[u] = *(const uint2*)r;
      vw[u] = *(const uint2*)(r + 512);
    }
#pragma unroll
    for (int u = 0; u < 8; u++) {
      float qx[4]; up_h4(qw[u], qx);
      float d = qx[0]*kx[0] + qx[1]*kx[1] + qx[2]*kx[2] + qx[3]*kx[3];
      d += __shfl_xor(d, 1); d += __shfl_xor(d, 2);
      d += __shfl_xor(d, 4); d += __shfl_xor(d, 8);
      float ex = __expf(fminf(fmaxf(d, -5.f), 5.f) * 8.f - 40.f);
      ex = (p + u < b1) ? ex : 0.f;
      den += ex;
      float vx[4]; up_h4(vw[u], vx);
      a0 += ex * vx[0]; a1 += ex * vx[1]; a2 += ex * vx[2]; a3 += ex * vx[3];
    }
  }
  float rd = 1.f / den;
  *(ushort4*)op = make_ushort4(f2bf(a0*rd), f2bf(a1*rd), f2bf(a2*rd), f2bf(a3*rd));
}

// ---- gate GEMV + gated residual + LN1 (-> h in d_out) + LN2 (-> bf16) ----
__device__ __forceinline__ float blkred(float v, float* sb)
{
#pragma unroll
  for (int s = 1; s < 64; s <<= 1) v += __shfl_xor(v, s);
  __syncthreads();
  if ((threadIdx.x & 63) == 0) sb[threadIdx.x >> 6] = v;
  __syncthreads();
  return sb[0] + sb[1];
}

__global__ __launch_bounds__(128) void k_gate_ln(const u16* __restrict__ rstb, const u16* __restrict__ skpb,
    const float* __restrict__ gA, const float* __restrict__ gB,
    const float* __restrict__ g1, const float* __restrict__ b1,
    const float* __restrict__ g2, const float* __restrict__ b2,
    float* __restrict__ hout, u16* __restrict__ h2b)
{
  __shared__ float sb[2];
  const int t = threadIdx.x;
  const size_t base = (size_t)blockIdx.x * FD + t * 4;
  ushort4 ru = *(const ushort4*)(rstb + base);
  ushort4 su = *(const ushort4*)(skpb + base);
  float r0 = bf2f(ru.x), r1 = bf2f(ru.y), r2 = bf2f(ru.z), r3 = bf2f(ru.w);
  float s0 = bf2f(su.x), s1 = bf2f(su.y), s2 = bf2f(su.z), s3 = bf2f(su.w);
  float4 av = *(const float4*)(gA + t * 4);
  float4 bv = *(const float4*)(gB + t * 4);
  float gd = r0*av.x + r1*av.y + r2*av.z + r3*av.w
           + s0*bv.x + s1*bv.y + s2*bv.z + s3*bv.w;
  float tot = blkred(gd, sb);
  float g = 1.f / (1.f + __expf(-tot));
  float x0 = g*r0 + (1.f-g)*s0;
  float x1 = g*r1 + (1.f-g)*s1;
  float x2 = g*r2 + (1.f-g)*s2;
  float x3 = g*r3 + (1.f-g)*s3;
  float m1 = blkred(x0+x1+x2+x3, sb) * (1.f/FD);
  float d0 = x0-m1, d1 = x1-m1, d2 = x2-m1, d3 = x3-m1;
  float v1 = blkred(d0*d0+d1*d1+d2*d2+d3*d3, sb) * (1.f/FD);
  float rs = rsqrtf(v1 + 1e-5f);
  float4 G1 = *(const float4*)(g1 + t*4);
  float4 Bb1 = *(const float4*)(b1 + t*4);
  float h0 = d0*rs*G1.x + Bb1.x;
  float h1 = d1*rs*G1.y + Bb1.y;
  float h2 = d2*rs*G1.z + Bb1.z;
  float h3 = d3*rs*G1.w + Bb1.w;
  *(float4*)(hout + base) = make_float4(h0, h1, h2, h3);
  float m2 = blkred(h0+h1+h2+h3, sb) * (1.f/FD);
  float e0 = h0-m2, e1 = h1-m2, e2 = h2-m2, e3 = h3-m2;
  float v2 = blkred(e0*e0+e1*e1+e2*e2+e3*e3, sb) * (1.f/FD);
  float rs2 = rsqrtf(v2 + 1e-5f);
  float4 G2 = *(const float4*)(g2 + t*4);
  float4 Bb2 = *(const float4*)(b2 + t*4);
  *(ushort4*)(h2b + base) = make_ushort4(
      f2bf(e0*rs2*G2.x + Bb2.x), f2bf(e1*rs2*G2.y + Bb2.y),
      f2bf(e2*rs2*G2.z + Bb2.z), f2bf(e3*rs2*G2.w + Bb2.w));
}

extern "C" void kernel_launch(void* const* d_in, const int* in_sizes, int n_in,
                              void* d_out, int out_size, void* d_ws, size_t ws_size,
                              hipStream_t stream)
{
  const float* feat = (const float*)d_in[0];
  const int* e_src = (const int*)d_in[1];
  const int* e_dst = (const int*)d_in[2];
  const float* Wq  = (const float*)d_in[3];
  const float* Wk  = (const float*)d_in[4];
  const float* Wv  = (const float*)d_in[5];
  const float* Wn  = (const float*)d_in[6];
  const float* Wsk = (const float*)d_in[7];
  const float* Wg  = (const float*)d_in[8];
  const float* l1g = (const float*)d_in[9];
  const float* l1b = (const float*)d_in[10];
  const float* l2g = (const float*)d_in[11];
  const float* l2b = (const float*)d_in[12];
  const float* W1  = (const float*)d_in[13];
  const float* W2  = (const float*)d_in[14];

  char* ws = (char*)d_ws;
  size_t o = 0;
  auto al = [&](size_t b) { char* r = ws + o; o = (o + b + 255) & ~(size_t)255; return r; };

  u16* Af    = (u16*)al((size_t)MP * FD * 2);      // feat fp16
  u16* Bqkvs = (u16*)al((size_t)2048 * FD * 2);    // [Wq|Wk|Wv|Wsk]^T fp16
  u16* Bnt   = (u16*)al((size_t)FD * FD * 2);
  u16* B1t   = (u16*)al((size_t)FD * FD * 2);
  u16* B2t   = (u16*)al((size_t)FD * FD * 2);
  float* gA  = (float*)al(FD * 4);
  float* gB  = (float*)al(FD * 4);
  u16* QV    = (u16*)al((size_t)MP * 1024 * 2);    // [q fp16 | v fp16] per node
  u16* Kb    = (u16*)al((size_t)MP * FD * 2);      // k fp16
  u16* SKIPb = (u16*)al((size_t)MP * FD * 2);      // bf16
  u16* aggb  = (u16*)al((size_t)MP * FD * 2);      // bf16
  u16* h2b   = (u16*)al((size_t)MP * FD * 2);      // bf16
  int* deg   = (int*)al((size_t)2 * NN * 4);
  int* cnt   = deg + NN;
  int* offa  = (int*)al((size_t)(NN + 1) * 4);
  int* esrcs = (int*)al((size_t)NE * 4);
  if (o > ws_size) return;  // ~150 MB needed
  // aliases into dead regions
  u16* rstb = Kb;    // Kb dead after k_edge
  u16* midb = Af;    // Af dead after QKVS GEMM
  float* out = (float*)d_out;

  hipMemsetAsync(deg, 0, (size_t)2 * NN * 4, stream);

  k_cvt_feat<<<dim3(MP * FD / 4 / 256), 256, 0, stream>>>(feat, Af);
  {
    int total = 2048 * 512 + 3 * 512 * 512 + 512;
    k_wprep<<<dim3((total + 255) / 256), 256, 0, stream>>>(Wq, Wk, Wv, Wsk, Wn, W1, W2, Wg,
        Bqkvs, Bnt, B1t, B2t, gA, gB);
  }

  // one fp16 GEMM for Q,K,V,SKIP  [MP x 2048 x 512]
  k_gemm<2048, 6, 1><<<dim3(MP / 128, 16), 256, 0, stream>>>(Af, Bqkvs, nullptr, QV, Kb, SKIPb, MP);

  k_deg<<<dim3((NE + 255) / 256), 256, 0, stream>>>(e_dst, deg);
  k_scan<<<dim3(1), 1024, 0, stream>>>(deg, offa);
  k_scatter<<<dim3((NE + 255) / 256), 256, 0, stream>>>(e_src, e_dst, offa, cnt, esrcs);
  k_edge<<<dim3(MP / 2), 256, 0, stream>>>(offa, esrcs, QV, Kb, aggb);

  k_gemm<512, 2, 0><<<dim3(MP / 128, 4), 256, 0, stream>>>(aggb, Bnt, nullptr, rstb, nullptr, nullptr, MP);
  k_gate_ln<<<dim3(NN), 128, 0, stream>>>(rstb, SKIPb, gA, gB, l1g, l1b, l2g, l2b, out, h2b);
  k_gemm<512, 1, 0><<<dim3(MP / 128, 4), 256, 0, stream>>>(h2b, B1t, nullptr, midb, nullptr, nullptr, MP);
  k_gemm<512, 3, 0><<<dim3(MP / 128, 4), 256, 0, stream>>>(midb, B2t, out, nullptr, nullptr, nullptr, NN);
}